// Round 9
// baseline (228.701 us; speedup 1.0000x reference)
//
#include <hip/hip_runtime.h>

#define S_LEN 8192
#define D_KK  128
// 1/sqrt(128) * log2(e): softmax runs in the exp2 domain
#define SCALE2 (0.08838834764831845f * 1.44269504088896340f)

typedef __bf16 bf16x2 __attribute__((ext_vector_type(2)));
typedef __bf16 bf16x4 __attribute__((ext_vector_type(4)));
typedef __bf16 bf16x8 __attribute__((ext_vector_type(8)));
typedef float  f32x16 __attribute__((ext_vector_type(16)));
typedef _Float16 half_t;

// ---------------------------------------------------------------------------
// Pre-pass: pack K and V into FRAGMENT-ORDER bf16 layouts (unchanged).
//   Kf[t*8+s][lane*8+j] = K[t*32 + (lane&31)][s*16 + (lane>>5)*8 + j]
//   Vf[t*8+f][lane*8+j] = V[t*32 + 16*(f&1) + 8*(lane>>5) + j][32*(f>>1) + (lane&31)]
// ---------------------------------------------------------------------------
__global__ __launch_bounds__(256) void prep_kv_23450521436217(
    const float* __restrict__ K,
    const float* __restrict__ V,
    __bf16* __restrict__ Kf,
    __bf16* __restrict__ Vf)
{
    const int tid = threadIdx.x;
    const int t   = blockIdx.x;
    __shared__ __bf16 T[32][140];

    const float* ktile = K + (size_t)t * 32 * D_KK;
    const float* vtile = V + (size_t)t * 32 * D_KK;

    const int row = tid & 31;
    const int cp  = tid >> 5;
    #pragma unroll
    for (int i = 0; i < 2; ++i) {
        int c = cp * 2 + i;
        int s = c >> 1, hi = c & 1;
        const float* src = ktile + row * D_KK + c * 8;
        float4 a = *(const float4*)(src);
        float4 b = *(const float4*)(src + 4);
        bf16x8 o;
        o[0]=(__bf16)a.x; o[1]=(__bf16)a.y; o[2]=(__bf16)a.z; o[3]=(__bf16)a.w;
        o[4]=(__bf16)b.x; o[5]=(__bf16)b.y; o[6]=(__bf16)b.z; o[7]=(__bf16)b.w;
        *(bf16x8*)(Kf + (size_t)(t * 8 + s) * 512 + hi * 256 + row * 8) = o;
    }

    #pragma unroll
    for (int i = 0; i < 4; ++i) {
        int f4 = tid + i * 256;
        float4 v = ((const float4*)vtile)[f4];
        int r = f4 >> 5, cc = (f4 & 31) << 2;
        bf16x4 b;
        b[0]=(__bf16)v.x; b[1]=(__bf16)v.y; b[2]=(__bf16)v.z; b[3]=(__bf16)v.w;
        *(bf16x4*)(&T[r][cc]) = b;
    }
    __syncthreads();

    #pragma unroll
    for (int i = 0; i < 2; ++i) {
        int idx  = tid + i * 256;
        int frag = idx >> 6, lane = idx & 63;
        int hi = lane >> 5, l5 = lane & 31;
        int d = frag >> 1, h = frag & 1;
        bf16x8 o;
        #pragma unroll
        for (int j = 0; j < 8; ++j) o[j] = T[16 * h + 8 * hi + j][32 * d + l5];
        *(bf16x8*)(Vf + (size_t)(t * 8 + frag) * 512 + lane * 8) = o;
    }
}

// ---------------------------------------------------------------------------
// Phase A: partial flash attention. Grid = 32 q-tiles x 8 kv-splits; block =
// 1024 thr = 16 waves = 4 waves/SIMD (occupancy doubled vs r8). Wave (wq,kvh):
// wq = q-subtile 0..7 (32 q-rows), kvh = intra-block kv half (512 keys,
// 16 iters of 32). K staged per-half into double-buffered LDS via
// global_load_lds; V fragments on the TA path. Softmax in exp2 domain.
// Intra-block pair-merge (kvh=1 -> LDS fp16 -> kvh=0 combines) keeps global
// partials at 8 per q-row; phase B unchanged.
// ---------------------------------------------------------------------------
__global__ __launch_bounds__(1024, 4) void attn_part_23450521436217(
    const float*  __restrict__ Q,
    const __bf16* __restrict__ Kf,
    const __bf16* __restrict__ Vf,
    half_t* __restrict__ P16,
    float*  __restrict__ Mp,
    float*  __restrict__ Lp)
{
    const int tid  = threadIdx.x;
    const int wave = tid >> 6;    // 0..15
    const int lane = tid & 63;
    const int l5   = lane & 31;   // q column (B ops) / A row (K,V ops)
    const int hi   = lane >> 5;   // k-half within MFMA
    const int wq   = wave & 7;    // q-subtile
    const int kvh  = wave >> 3;   // kv half

    const int ks   = blockIdx.x & 7;   // kv split (XCD-aligned)
    const int qt   = blockIdx.x >> 3;  // q-tile 0..31
    const int qsub = qt * 8 + wq;      // global 32-row q-subtile id
    const int qrow = qsub * 32 + l5;

    __shared__ __align__(16) __bf16 Klds[2][2][4096];  // [kvh][buf], 32 KB
    __shared__ float Mx[8][32], Lx[8][32];

    // Q fragments (B operand), SCALE2 folded in (exp2-domain softmax)
    bf16x8 qf[8];
    #pragma unroll
    for (int s = 0; s < 8; ++s) {
        const float* qp = Q + (size_t)qrow * D_KK + s * 16 + hi * 8;
        float4 a = *(const float4*)(qp);
        float4 b = *(const float4*)(qp + 4);
        bf16x8 f;
        f[0]=(__bf16)(a.x*SCALE2); f[1]=(__bf16)(a.y*SCALE2);
        f[2]=(__bf16)(a.z*SCALE2); f[3]=(__bf16)(a.w*SCALE2);
        f[4]=(__bf16)(b.x*SCALE2); f[5]=(__bf16)(b.y*SCALE2);
        f[6]=(__bf16)(b.z*SCALE2); f[7]=(__bf16)(b.w*SCALE2);
        qf[s] = f;
    }

    f32x16 oacc[4];
    #pragma unroll
    for (int d = 0; d < 4; ++d) oacc[d] = f32x16{};
    float m_run = -1e30f, l_run = 0.0f;

    // this half's 16 K/V tiles
    const __bf16* kbase = Kf + (size_t)(ks * 32 + kvh * 16) * 4096;
    const __bf16* vfp   = Vf + (size_t)(ks * 32 + kvh * 16) * 4096 + lane * 8;

    // prologue: stage K tile 0 (each wave stages 1KB of its half's tile)
    {
        const __bf16* src = kbase + wq * 512 + lane * 8;
        __builtin_amdgcn_global_load_lds(
            (const __attribute__((address_space(1))) void*)src,
            (__attribute__((address_space(3))) void*)&Klds[kvh][0][wq * 512],
            16, 0, 0);
    }
    __syncthreads();

    for (int it = 0; it < 16; ++it) {
        const int cur = it & 1;

        // stage K(it+1) into the other buffer (completes at the barrier)
        if (it < 15) {
            const __bf16* src = kbase + (size_t)(it + 1) * 4096 + wq * 512 + lane * 8;
            __builtin_amdgcn_global_load_lds(
                (const __attribute__((address_space(1))) void*)src,
                (__attribute__((address_space(3))) void*)&Klds[kvh][cur ^ 1][wq * 512],
                16, 0, 0);
        }

        // V fragments for this iter (TA path; latency hidden under QK+SM)
        const __bf16* vt = vfp + (size_t)it * 4096;
        bf16x8 vb[8];
        #pragma unroll
        for (int f = 0; f < 8; ++f) vb[f] = *(const bf16x8*)(vt + f * 512);

        // QK^T swapped from LDS: S^T[key][q], key=(r&3)+8*(r>>2)+4*hi, q=l5
        f32x16 c = f32x16{};
        __builtin_amdgcn_s_setprio(1);
        #pragma unroll
        for (int s = 0; s < 8; ++s) {
            bf16x8 kf = *(const bf16x8*)(&Klds[kvh][cur][s * 512 + lane * 8]);
            c = __builtin_amdgcn_mfma_f32_32x32x16_bf16(kf, qf[s], c, 0, 0, 0);
        }
        __builtin_amdgcn_s_setprio(0);

        // online softmax (exp2 domain): pairwise max tree, defer-max THR=11.5
        float x0 = fmaxf(c[0], c[8]),  x1 = fmaxf(c[1], c[9]);
        float x2 = fmaxf(c[2], c[10]), x3 = fmaxf(c[3], c[11]);
        float x4 = fmaxf(c[4], c[12]), x5 = fmaxf(c[5], c[13]);
        float x6 = fmaxf(c[6], c[14]), x7 = fmaxf(c[7], c[15]);
        float y0 = fmaxf(fmaxf(x0, x4), fmaxf(x1, x5));
        float y1 = fmaxf(fmaxf(x2, x6), fmaxf(x3, x7));
        float tmax = fmaxf(y0, y1);
        tmax = fmaxf(tmax, __shfl_xor(tmax, 32));
        if (__any(tmax > m_run + 11.5f)) {
            float mnew  = fmaxf(m_run, tmax);
            float alpha = exp2f(m_run - mnew);
            #pragma unroll
            for (int d = 0; d < 4; ++d) oacc[d] *= alpha;
            l_run *= alpha;
            m_run  = mnew;
        }
        float p[16];
        #pragma unroll
        for (int r = 0; r < 16; ++r) p[r] = exp2f(c[r] - m_run);
        float s0a = (p[0]+p[1]) + (p[2]+p[3]),   s1a = (p[4]+p[5]) + (p[6]+p[7]);
        float s2a = (p[8]+p[9]) + (p[10]+p[11]), s3a = (p[12]+p[13]) + (p[14]+p[15]);
        float ps = (s0a + s1a) + (s2a + s3a);
        ps += __shfl_xor(ps, 32);
        l_run += ps;

        // P -> bf16 packs; permlane32_swap -> PV B-operand words
        unsigned pk[8];
        #pragma unroll
        for (int tq = 0; tq < 8; ++tq) {
            bf16x2 w; w[0] = (__bf16)p[2*tq]; w[1] = (__bf16)p[2*tq+1];
            pk[tq] = __builtin_bit_cast(unsigned, w);
        }
        asm volatile("v_permlane32_swap_b32 %0, %1" : "+v"(pk[0]), "+v"(pk[2]));
        asm volatile("v_permlane32_swap_b32 %0, %1" : "+v"(pk[1]), "+v"(pk[3]));
        asm volatile("v_permlane32_swap_b32 %0, %1" : "+v"(pk[4]), "+v"(pk[6]));
        asm volatile("v_permlane32_swap_b32 %0, %1" : "+v"(pk[5]), "+v"(pk[7]));
        union { unsigned u[4]; bf16x8 f; } b0, b1;
        b0.u[0]=pk[0]; b0.u[1]=pk[1]; b0.u[2]=pk[2]; b0.u[3]=pk[3];
        b1.u[0]=pk[4]; b1.u[1]=pk[5]; b1.u[2]=pk[6]; b1.u[3]=pk[7];

        // PV: O^T[d][q] += V^T * P^T
        __builtin_amdgcn_s_setprio(1);
        #pragma unroll
        for (int d = 0; d < 4; ++d) {
            oacc[d] = __builtin_amdgcn_mfma_f32_32x32x16_bf16(vb[2*d+0], b0.f,
                                                              oacc[d], 0,0,0);
            oacc[d] = __builtin_amdgcn_mfma_f32_32x32x16_bf16(vb[2*d+1], b1.f,
                                                              oacc[d], 0,0,0);
        }
        __builtin_amdgcn_s_setprio(0);

        __syncthreads();   // K(it+1) staged + all waves done with buf[cur]
    }

    // ---- intra-block pair merge (kvh=1 publishes, kvh=0 combines) ----
    // Klds repurposed as 4 x fp16[128*32] merge buffers (K loop is done).
    half_t* mrgbase = (half_t*)Klds;

    if (kvh == 1 && lane < 32) { Mx[wq][lane] = m_run; Lx[wq][lane] = l_run; }

    for (int r = 0; r < 2; ++r) {
        if (kvh == 1 && (wq >> 2) == r) {
            half_t* mb = mrgbase + (size_t)(wq & 3) * 4096;
            #pragma unroll
            for (int d = 0; d < 4; ++d)
                #pragma unroll
                for (int reg = 0; reg < 16; ++reg) {
                    int drow = d * 32 + (reg & 3) + 8 * (reg >> 2) + 4 * hi;
                    mb[drow * 32 + l5] = (half_t)oacc[d][reg];
                }
        }
        __syncthreads();
        if (kvh == 0 && (wq >> 2) == r) {
            float m1 = Mx[wq][l5], l1 = Lx[wq][l5];
            float M  = fmaxf(m_run, m1);
            float w0 = exp2f(m_run - M), w1 = exp2f(m1 - M);
            if (lane < 32) {
                Mp[ks * S_LEN + qrow] = M;
                Lp[ks * S_LEN + qrow] = l_run * w0 + l1 * w1;
            }
            const half_t* mb = mrgbase + (size_t)(wq & 3) * 4096;
            half_t* pb = P16 + (size_t)(ks * 256 + qsub) * 4096;
            #pragma unroll
            for (int d = 0; d < 4; ++d)
                #pragma unroll
                for (int reg = 0; reg < 16; ++reg) {
                    int drow = d * 32 + (reg & 3) + 8 * (reg >> 2) + 4 * hi;
                    pb[drow * 32 + l5] =
                        (half_t)(oacc[d][reg] * w0 + (float)mb[drow * 32 + l5] * w1);
                }
        }
        __syncthreads();
    }
}

// ---------------------------------------------------------------------------
// Phase B: merge 8 kv-split partials per q-row (m in exp2 domain).
// ---------------------------------------------------------------------------
__global__ __launch_bounds__(256) void attn_merge_23450521436217(
    const half_t* __restrict__ P16,
    const float*  __restrict__ Mp,
    const float*  __restrict__ Lp,
    float* __restrict__ O)
{
    const int tid  = threadIdx.x;
    const int qsub = blockIdx.x;

    __shared__ float W[8][32];
    __shared__ float Li[32];
    __shared__ float Ot[128][33];

    if (tid < 32) {
        const int qrow = qsub * 32 + tid;
        float m[8], l[8];
        #pragma unroll
        for (int ks = 0; ks < 8; ++ks) {
            m[ks] = Mp[ks * S_LEN + qrow];
            l[ks] = Lp[ks * S_LEN + qrow];
        }
        float M = m[0];
        #pragma unroll
        for (int ks = 1; ks < 8; ++ks) M = fmaxf(M, m[ks]);
        float L = 0.0f;
        #pragma unroll
        for (int ks = 0; ks < 8; ++ks) {
            float w = exp2f(m[ks] - M);
            W[ks][tid] = w;
            L += l[ks] * w;
        }
        Li[tid] = 1.0f / L;
    }
    __syncthreads();

    const int q  = tid & 31;
    const int dg = tid >> 5;          // 0..7
    #pragma unroll
    for (int j = 0; j < 16; ++j) {
        const int d = dg * 16 + j;
        float acc = 0.0f;
        #pragma unroll
        for (int ks = 0; ks < 8; ++ks)
            acc += W[ks][q] *
                   (float)P16[(size_t)(ks * 256 + qsub) * (128 * 32) + d * 32 + q];
        Ot[d][q] = acc;
    }
    __syncthreads();

    const int qq = tid >> 3;
    const int dv = (tid & 7) * 16;
    const float il = Li[qq];
    float* op = O + (size_t)(qsub * 32 + qq) * D_KK + dv;
    #pragma unroll
    for (int i = 0; i < 4; ++i) {
        float4 o;
        o.x = Ot[dv + i*4 + 0][qq] * il;
        o.y = Ot[dv + i*4 + 1][qq] * il;
        o.z = Ot[dv + i*4 + 2][qq] * il;
        o.w = Ot[dv + i*4 + 3][qq] * il;
        ((float4*)op)[i] = o;
    }
}

extern "C" void kernel_launch(void* const* d_in, const int* in_sizes, int n_in,
                              void* d_out, int out_size, void* d_ws, size_t ws_size,
                              hipStream_t stream) {
    const float* Q = (const float*)d_in[0];
    const float* K = (const float*)d_in[1];
    const float* V = (const float*)d_in[2];
    float* O = (float*)d_out;

    char* ws = (char*)d_ws;
    const size_t kf_b = (size_t)S_LEN * D_KK * 2;        // 2 MB
    __bf16* Kf = (__bf16*)(ws);
    __bf16* Vf = (__bf16*)(ws + kf_b);
    float*  Mp = (float*) (ws + 2 * kf_b);               // 256 KB
    float*  Lp = (float*) (ws + 2 * kf_b + 8 * S_LEN * 4);
    half_t* P16= (half_t*)(ws + 2 * kf_b + 16 * S_LEN * 4);  // 16.8 MB

    hipLaunchKernelGGL(prep_kv_23450521436217, dim3(S_LEN/32), dim3(256), 0, stream,
                       K, V, Kf, Vf);
    hipLaunchKernelGGL(attn_part_23450521436217, dim3(256), dim3(1024), 0, stream,
                       Q, Kf, Vf, P16, Mp, Lp);
    hipLaunchKernelGGL(attn_merge_23450521436217, dim3(S_LEN/32), dim3(256), 0, stream,
                       P16, Mp, Lp, O);
}

// Round 10
// 90.558 us; speedup vs baseline: 2.5255x; 2.5255x over previous
//
#include <hip/hip_runtime.h>

#define S_LEN 8192
#define D_KK  128
// 1/sqrt(128) * log2(e): softmax runs in the exp2 domain
#define SCALE2 (0.08838834764831845f * 1.44269504088896340f)

typedef __bf16 bf16x2 __attribute__((ext_vector_type(2)));
typedef __bf16 bf16x4 __attribute__((ext_vector_type(4)));
typedef __bf16 bf16x8 __attribute__((ext_vector_type(8)));
typedef float  f32x16 __attribute__((ext_vector_type(16)));
typedef _Float16 half_t;

// ---------------------------------------------------------------------------
// Pre-pass: pack K and V into FRAGMENT-ORDER bf16 layouts (unchanged).
//   Kf[t*8+s][lane*8+j] = K[t*32 + (lane&31)][s*16 + (lane>>5)*8 + j]
//   Vf[t*8+f][lane*8+j] = V[t*32 + 16*(f&1) + 8*(lane>>5) + j][32*(f>>1) + (lane&31)]
// ---------------------------------------------------------------------------
__global__ __launch_bounds__(256) void prep_kv_23450521436217(
    const float* __restrict__ K,
    const float* __restrict__ V,
    __bf16* __restrict__ Kf,
    __bf16* __restrict__ Vf)
{
    const int tid = threadIdx.x;
    const int t   = blockIdx.x;
    __shared__ __bf16 T[32][140];

    const float* ktile = K + (size_t)t * 32 * D_KK;
    const float* vtile = V + (size_t)t * 32 * D_KK;

    const int row = tid & 31;
    const int cp  = tid >> 5;
    #pragma unroll
    for (int i = 0; i < 2; ++i) {
        int c = cp * 2 + i;
        int s = c >> 1, hi = c & 1;
        const float* src = ktile + row * D_KK + c * 8;
        float4 a = *(const float4*)(src);
        float4 b = *(const float4*)(src + 4);
        bf16x8 o;
        o[0]=(__bf16)a.x; o[1]=(__bf16)a.y; o[2]=(__bf16)a.z; o[3]=(__bf16)a.w;
        o[4]=(__bf16)b.x; o[5]=(__bf16)b.y; o[6]=(__bf16)b.z; o[7]=(__bf16)b.w;
        *(bf16x8*)(Kf + (size_t)(t * 8 + s) * 512 + hi * 256 + row * 8) = o;
    }

    #pragma unroll
    for (int i = 0; i < 4; ++i) {
        int f4 = tid + i * 256;
        float4 v = ((const float4*)vtile)[f4];
        int r = f4 >> 5, cc = (f4 & 31) << 2;
        bf16x4 b;
        b[0]=(__bf16)v.x; b[1]=(__bf16)v.y; b[2]=(__bf16)v.z; b[3]=(__bf16)v.w;
        *(bf16x4*)(&T[r][cc]) = b;
    }
    __syncthreads();

    #pragma unroll
    for (int i = 0; i < 2; ++i) {
        int idx  = tid + i * 256;
        int frag = idx >> 6, lane = idx & 63;
        int hi = lane >> 5, l5 = lane & 31;
        int d = frag >> 1, h = frag & 1;
        bf16x8 o;
        #pragma unroll
        for (int j = 0; j < 8; ++j) o[j] = T[16 * h + 8 * hi + j][32 * d + l5];
        *(bf16x8*)(Vf + (size_t)(t * 8 + frag) * 512 + lane * 8) = o;
    }
}

// ---------------------------------------------------------------------------
// Phase A: partial flash attention, SPLIT-PV wave pairs.
// Grid = 32 q-tiles x 8 kv-splits. Block = 1024 thr = 16 waves = 4 waves/SIMD
// (launch_bounds(1024,1) -> hard 128-VGPR cap, no min-blocks clamp).
// Wave (wq = wave&7, dh = wave>>3): both waves of a pair redundantly compute
// QK^T + softmax for q-subtile wq (fills former stall cycles); PV is split by
// d-half (dh) -> oacc 32 regs, vb 16 regs -> fits the 128-reg budget.
// K tiles double-buffered in LDS (staged by dh=0 waves via global_load_lds);
// V fragments loaded late (after P-pack) to minimize live ranges.
// Writes per-split partials (m, l, unnormalized O^T fp16, d-half each).
// ---------------------------------------------------------------------------
__global__ __launch_bounds__(1024, 1) void attn_part_23450521436217(
    const float*  __restrict__ Q,
    const __bf16* __restrict__ Kf,
    const __bf16* __restrict__ Vf,
    half_t* __restrict__ P16,
    float*  __restrict__ Mp,
    float*  __restrict__ Lp)
{
    const int tid  = threadIdx.x;
    const int wave = tid >> 6;    // 0..15
    const int lane = tid & 63;
    const int l5   = lane & 31;   // q column (B ops) / A row (K,V ops)
    const int hi   = lane >> 5;   // k-half within MFMA
    const int wq   = wave & 7;    // q-subtile
    const int dh   = wave >> 3;   // d-half for PV

    const int ks   = blockIdx.x & 7;   // kv split (XCD-aligned)
    const int qt   = blockIdx.x >> 3;  // q-tile 0..31
    const int qsub = qt * 8 + wq;      // global 32-row q-subtile id
    const int qrow = qsub * 32 + l5;

    __shared__ __align__(16) __bf16 Klds[2][4096];   // 2 x 8KB K tiles

    // Q fragments (B operand), SCALE2 folded in (exp2-domain softmax)
    bf16x8 qf[8];
    #pragma unroll
    for (int s = 0; s < 8; ++s) {
        const float* qp = Q + (size_t)qrow * D_KK + s * 16 + hi * 8;
        float4 a = *(const float4*)(qp);
        float4 b = *(const float4*)(qp + 4);
        bf16x8 f;
        f[0]=(__bf16)(a.x*SCALE2); f[1]=(__bf16)(a.y*SCALE2);
        f[2]=(__bf16)(a.z*SCALE2); f[3]=(__bf16)(a.w*SCALE2);
        f[4]=(__bf16)(b.x*SCALE2); f[5]=(__bf16)(b.y*SCALE2);
        f[6]=(__bf16)(b.z*SCALE2); f[7]=(__bf16)(b.w*SCALE2);
        qf[s] = f;
    }

    // PV accumulators for this wave's 64-dim half (d-blocks 2dh, 2dh+1)
    f32x16 oacc0 = f32x16{}, oacc1 = f32x16{};
    float m_run = -1e30f, l_run = 0.0f;

    const __bf16* kbase = Kf + (size_t)(ks * 32) * 4096;             // 32 tiles
    const __bf16* vfp   = Vf + (size_t)(ks * 32) * 4096 + lane * 8
                             + (size_t)(dh * 4) * 512;               // d-half base

    // prologue: dh=0 waves stage K tile 0 (1KB fragment-block each)
    if (dh == 0) {
        const __bf16* src = kbase + wq * 512 + lane * 8;
        __builtin_amdgcn_global_load_lds(
            (const __attribute__((address_space(1))) void*)src,
            (__attribute__((address_space(3))) void*)&Klds[0][wq * 512],
            16, 0, 0);
    }
    __syncthreads();

    for (int it = 0; it < 32; ++it) {
        const int cur = it & 1;

        // stage K(it+1) into the other buffer (completes at the barrier)
        if (dh == 0 && it < 31) {
            const __bf16* src = kbase + (size_t)(it + 1) * 4096 + wq * 512 + lane * 8;
            __builtin_amdgcn_global_load_lds(
                (const __attribute__((address_space(1))) void*)src,
                (__attribute__((address_space(3))) void*)&Klds[cur ^ 1][wq * 512],
                16, 0, 0);
        }

        // QK^T swapped from LDS: S^T[key][q], key=(r&3)+8*(r>>2)+4*hi, q=l5
        f32x16 c = f32x16{};
        __builtin_amdgcn_s_setprio(1);
        #pragma unroll
        for (int s = 0; s < 8; ++s) {
            bf16x8 kf = *(const bf16x8*)(&Klds[cur][s * 512 + lane * 8]);
            c = __builtin_amdgcn_mfma_f32_32x32x16_bf16(kf, qf[s], c, 0, 0, 0);
        }
        __builtin_amdgcn_s_setprio(0);

        // online softmax (exp2 domain): pairwise max tree, defer-max THR=11.5
        float x0 = fmaxf(c[0], c[8]),  x1 = fmaxf(c[1], c[9]);
        float x2 = fmaxf(c[2], c[10]), x3 = fmaxf(c[3], c[11]);
        float x4 = fmaxf(c[4], c[12]), x5 = fmaxf(c[5], c[13]);
        float x6 = fmaxf(c[6], c[14]), x7 = fmaxf(c[7], c[15]);
        float y0 = fmaxf(fmaxf(x0, x4), fmaxf(x1, x5));
        float y1 = fmaxf(fmaxf(x2, x6), fmaxf(x3, x7));
        float tmax = fmaxf(y0, y1);
        tmax = fmaxf(tmax, __shfl_xor(tmax, 32));
        if (__any(tmax > m_run + 11.5f)) {
            float mnew  = fmaxf(m_run, tmax);
            float alpha = exp2f(m_run - mnew);
            oacc0 *= alpha;
            oacc1 *= alpha;
            l_run *= alpha;
            m_run  = mnew;
        }
        float p[16];
        #pragma unroll
        for (int r = 0; r < 16; ++r) p[r] = exp2f(c[r] - m_run);
        float s0a = (p[0]+p[1]) + (p[2]+p[3]),   s1a = (p[4]+p[5]) + (p[6]+p[7]);
        float s2a = (p[8]+p[9]) + (p[10]+p[11]), s3a = (p[12]+p[13]) + (p[14]+p[15]);
        float ps = (s0a + s1a) + (s2a + s3a);
        ps += __shfl_xor(ps, 32);
        l_run += ps;

        // P -> bf16 packs; permlane32_swap -> PV B-operand words
        unsigned pk[8];
        #pragma unroll
        for (int tq = 0; tq < 8; ++tq) {
            bf16x2 w; w[0] = (__bf16)p[2*tq]; w[1] = (__bf16)p[2*tq+1];
            pk[tq] = __builtin_bit_cast(unsigned, w);
        }
        asm volatile("v_permlane32_swap_b32 %0, %1" : "+v"(pk[0]), "+v"(pk[2]));
        asm volatile("v_permlane32_swap_b32 %0, %1" : "+v"(pk[1]), "+v"(pk[3]));
        asm volatile("v_permlane32_swap_b32 %0, %1" : "+v"(pk[4]), "+v"(pk[6]));
        asm volatile("v_permlane32_swap_b32 %0, %1" : "+v"(pk[5]), "+v"(pk[7]));
        union { unsigned u[4]; bf16x8 f; } b0, b1;
        b0.u[0]=pk[0]; b0.u[1]=pk[1]; b0.u[2]=pk[2]; b0.u[3]=pk[3];
        b1.u[0]=pk[4]; b1.u[1]=pk[5]; b1.u[2]=pk[6]; b1.u[3]=pk[7];

        // V fragments for this wave's d-half (loaded late; TLP hides latency)
        const __bf16* vt = vfp + (size_t)it * 4096;
        bf16x8 v0 = *(const bf16x8*)(vt);
        bf16x8 v1 = *(const bf16x8*)(vt + 512);
        bf16x8 v2 = *(const bf16x8*)(vt + 1024);
        bf16x8 v3 = *(const bf16x8*)(vt + 1536);

        // PV: O^T[d][q] += V^T * P^T (4 MFMAs, this d-half only)
        __builtin_amdgcn_s_setprio(1);
        oacc0 = __builtin_amdgcn_mfma_f32_32x32x16_bf16(v0, b0.f, oacc0, 0, 0, 0);
        oacc0 = __builtin_amdgcn_mfma_f32_32x32x16_bf16(v1, b1.f, oacc0, 0, 0, 0);
        oacc1 = __builtin_amdgcn_mfma_f32_32x32x16_bf16(v2, b0.f, oacc1, 0, 0, 0);
        oacc1 = __builtin_amdgcn_mfma_f32_32x32x16_bf16(v3, b1.f, oacc1, 0, 0, 0);
        __builtin_amdgcn_s_setprio(0);

        __syncthreads();   // K(it+1) staged + all waves done with buf[cur]
    }

    // ---- write partials (this wave's 64-dim half) ----
    if (dh == 0 && lane < 32) {
        Mp[ks * S_LEN + qrow] = m_run;
        Lp[ks * S_LEN + qrow] = l_run;
    }
    half_t* pb = P16 + (size_t)(ks * 256 + qsub) * 4096;
    #pragma unroll
    for (int reg = 0; reg < 16; ++reg) {
        int drow0 = (2*dh + 0) * 32 + (reg & 3) + 8 * (reg >> 2) + 4 * hi;
        int drow1 = (2*dh + 1) * 32 + (reg & 3) + 8 * (reg >> 2) + 4 * hi;
        pb[drow0 * 32 + l5] = (half_t)oacc0[reg];
        pb[drow1 * 32 + l5] = (half_t)oacc1[reg];
    }
}

// ---------------------------------------------------------------------------
// Phase B: merge 8 kv-split partials per q-row (m in exp2 domain).
// ---------------------------------------------------------------------------
__global__ __launch_bounds__(256) void attn_merge_23450521436217(
    const half_t* __restrict__ P16,
    const float*  __restrict__ Mp,
    const float*  __restrict__ Lp,
    float* __restrict__ O)
{
    const int tid  = threadIdx.x;
    const int qsub = blockIdx.x;

    __shared__ float W[8][32];
    __shared__ float Li[32];
    __shared__ float Ot[128][33];

    if (tid < 32) {
        const int qrow = qsub * 32 + tid;
        float m[8], l[8];
        #pragma unroll
        for (int ks = 0; ks < 8; ++ks) {
            m[ks] = Mp[ks * S_LEN + qrow];
            l[ks] = Lp[ks * S_LEN + qrow];
        }
        float M = m[0];
        #pragma unroll
        for (int ks = 1; ks < 8; ++ks) M = fmaxf(M, m[ks]);
        float L = 0.0f;
        #pragma unroll
        for (int ks = 0; ks < 8; ++ks) {
            float w = exp2f(m[ks] - M);
            W[ks][tid] = w;
            L += l[ks] * w;
        }
        Li[tid] = 1.0f / L;
    }
    __syncthreads();

    const int q  = tid & 31;
    const int dg = tid >> 5;          // 0..7
    #pragma unroll
    for (int j = 0; j < 16; ++j) {
        const int d = dg * 16 + j;
        float acc = 0.0f;
        #pragma unroll
        for (int ks = 0; ks < 8; ++ks)
            acc += W[ks][q] *
                   (float)P16[(size_t)(ks * 256 + qsub) * (128 * 32) + d * 32 + q];
        Ot[d][q] = acc;
    }
    __syncthreads();

    const int qq = tid >> 3;
    const int dv = (tid & 7) * 16;
    const float il = Li[qq];
    float* op = O + (size_t)(qsub * 32 + qq) * D_KK + dv;
    #pragma unroll
    for (int i = 0; i < 4; ++i) {
        float4 o;
        o.x = Ot[dv + i*4 + 0][qq] * il;
        o.y = Ot[dv + i*4 + 1][qq] * il;
        o.z = Ot[dv + i*4 + 2][qq] * il;
        o.w = Ot[dv + i*4 + 3][qq] * il;
        ((float4*)op)[i] = o;
    }
}

extern "C" void kernel_launch(void* const* d_in, const int* in_sizes, int n_in,
                              void* d_out, int out_size, void* d_ws, size_t ws_size,
                              hipStream_t stream) {
    const float* Q = (const float*)d_in[0];
    const float* K = (const float*)d_in[1];
    const float* V = (const float*)d_in[2];
    float* O = (float*)d_out;

    char* ws = (char*)d_ws;
    const size_t kf_b = (size_t)S_LEN * D_KK * 2;        // 2 MB
    __bf16* Kf = (__bf16*)(ws);
    __bf16* Vf = (__bf16*)(ws + kf_b);
    float*  Mp = (float*) (ws + 2 * kf_b);               // 256 KB
    float*  Lp = (float*) (ws + 2 * kf_b + 8 * S_LEN * 4);
    half_t* P16= (half_t*)(ws + 2 * kf_b + 16 * S_LEN * 4);  // 16.8 MB

    hipLaunchKernelGGL(prep_kv_23450521436217, dim3(S_LEN/32), dim3(256), 0, stream,
                       K, V, Kf, Vf);
    hipLaunchKernelGGL(attn_part_23450521436217, dim3(256), dim3(1024), 0, stream,
                       Q, Kf, Vf, P16, Mp, Lp);
    hipLaunchKernelGGL(attn_merge_23450521436217, dim3(S_LEN/32), dim3(256), 0, stream,
                       P16, Mp, Lp, O);
}